// Round 6
// baseline (1075.092 us; speedup 1.0000x reference)
//
#include <hip/hip_runtime.h>
#include <cstdint>

// ---------- types ----------
using short8 = __attribute__((ext_vector_type(8))) short;
using f32x4  = __attribute__((ext_vector_type(4))) float;
typedef unsigned short ushort_t;

// ---------- bf16 helpers ----------
__device__ __forceinline__ ushort_t f2bf(float f) {
    union { float f; unsigned int u; } v; v.f = f;
    unsigned int r = v.u + 0x7FFFu + ((v.u >> 16) & 1u);   // RNE
    return (ushort_t)(r >> 16);
}
__device__ __forceinline__ float bf2f(ushort_t s) {
    union { unsigned int u; float f; } v; v.u = ((unsigned int)s) << 16;
    return v.f;
}
__device__ __forceinline__ float sigmoidf(float x) { return 1.f / (1.f + expf(-x)); }

__device__ __forceinline__ void async_copy16(void* lds, const void* g) {
    __builtin_amdgcn_global_load_lds((__attribute__((address_space(1))) void*)g,
                                     (__attribute__((address_space(3))) void*)lds,
                                     16, 0, 0);
}

// ---------- constants ----------
// complete 4-ary tree, leaves-first: levels 16384 4096 1024 256 64 16 4 1 (N=21845)
// bf16x3: effective K=1536. A-side stored [hi|lo] (KA=1024), 3rd segment re-reads hi
// via pointer wrap. B-side stored [hi|hi|lo] (KB=1536).
#define KA 1024
#define KB 1536
#define NLEAF 16384
#define NNODE 21845
#define NINT  5461

// ---------- workspace layout (bytes), total 152,412,160 (~152.4 MB) ----------
#define OFF_WTIOUX  0UL
#define OFF_WTIOUH  (OFF_WTIOUX + 1536UL*KB*2)
#define OFF_WTFX    (OFF_WTIOUH + 1536UL*KB*2)
#define OFF_WTFH    (OFF_WTFX   + 512UL*KB*2)
#define OFF_BIASIOU (OFF_WTFH   + 512UL*KB*2)
#define OFF_BIASF   (OFF_BIASIOU + 1536UL*4)
#define OFF_XHL     (OFF_BIASF  + 512UL*4)
// x_hl: 21848 rows x [hi|lo]. Leaf-x rows 0..16383 become h_int rows 0..5460 after the
// leaf dispatch (leaf x dead then; writes to rows [off-NLEAF, ...) never overlap the
// still-live internal-x rows [16384, 21845) nor the previous level's h rows).
#define OFF_HLEAF   (OFF_XHL    + 21848UL*KA*2)
// h_leaf: 16384 x [hi|lo] = 33.5 MB. After l1's hsum+f-GEMM consume it, its first
// 11.2 MB double as c_int (internal-node c, 5464 x 512 fp32) — first write is l1's
// fused epilogue, which runs after both consumers.
#define OFF_XF      (OFF_HLEAF  + 16384UL*KA*2)
#define OFF_HSUM    (OFF_XF     + 5464UL*512*4)
#define OFF_CLEAF   (OFF_HSUM   + 4096UL*KA*2)
#define OFF_FC      (OFF_CLEAF  + 16384UL*512*4)
// end = OFF_FC + 4096*512*4 = 152,412,160

// ---------- prep: transpose fp32 W (KxN) -> N x KB bf16, B-side [hi|hi|lo] ----------
__global__ void wsplit_kernel(const float* __restrict__ in, ushort_t* __restrict__ out, int N) {
    __shared__ float t[32][33];
    int kb = blockIdx.x * 32, nb = blockIdx.y * 32;
    for (int i = threadIdx.y; i < 32; i += 8)
        t[i][threadIdx.x] = in[(size_t)(kb + i) * N + nb + threadIdx.x];
    __syncthreads();
    for (int i = threadIdx.y; i < 32; i += 8) {
        float v = t[threadIdx.x][i];
        ushort_t hi = f2bf(v);
        ushort_t lo = f2bf(v - bf2f(hi));
        size_t row = (size_t)(nb + i) * KB + kb + threadIdx.x;
        out[row]        = hi;   // pairs with A hi
        out[row + 512]  = hi;   // pairs with A lo
        out[row + 1024] = lo;   // pairs with A hi (wrapped)
    }
}

__global__ void bias_kernel(const float* __restrict__ b_ioux, const float* __restrict__ b_iouh,
                            const float* __restrict__ b_fx, const float* __restrict__ b_fh,
                            float* __restrict__ bias_iou, float* __restrict__ bias_f) {
    int t = blockIdx.x * blockDim.x + threadIdx.x;
    if (t < 1536) bias_iou[t] = b_ioux[t] + b_iouh[t];
    if (t < 512)  bias_f[t]   = b_fx[t] + b_fh[t];
}

// ---------- all x rows -> A-side [hi|lo], 4 elems/thread ----------
__global__ void xexp_kernel(const float* __restrict__ x, ushort_t* __restrict__ xe, int n4) {
    int t = blockIdx.x * blockDim.x + threadIdx.x;
    if (t >= n4) return;
    int j = t >> 7, m4 = (t & 127) * 4;
    float4 v = *(const float4*)&x[(size_t)j * 512 + m4];
    ushort4 hi, lo;
    hi.x = f2bf(v.x); lo.x = f2bf(v.x - bf2f(hi.x));
    hi.y = f2bf(v.y); lo.y = f2bf(v.y - bf2f(hi.y));
    hi.z = f2bf(v.z); lo.z = f2bf(v.z - bf2f(hi.z));
    hi.w = f2bf(v.w); lo.w = f2bf(v.w - bf2f(hi.w));
    ushort_t* row = xe + (size_t)j * KA;
    *(ushort4*)&row[m4] = hi;
    *(ushort4*)&row[512 + m4] = lo;
}

// ---------- hsum of 4 children (exact h = hi+lo) -> A-side [hi|lo] ----------
__global__ void hsum_kernel(const ushort_t* __restrict__ h_hl, ushort_t* __restrict__ hsum_hl,
                            int n4) {
    int t = blockIdx.x * blockDim.x + threadIdx.x;
    if (t >= n4) return;
    int j = t >> 7, m4 = (t & 127) * 4;
    const ushort_t* base = h_hl + (size_t)(4 * j) * KA;
    float s0 = 0.f, s1 = 0.f, s2 = 0.f, s3 = 0.f;
#pragma unroll
    for (int r = 0; r < 4; ++r) {
        ushort4 h4 = *(const ushort4*)&base[(size_t)r * KA + m4];
        ushort4 l4 = *(const ushort4*)&base[(size_t)r * KA + 512 + m4];
        s0 += bf2f(h4.x) + bf2f(l4.x);
        s1 += bf2f(h4.y) + bf2f(l4.y);
        s2 += bf2f(h4.z) + bf2f(l4.z);
        s3 += bf2f(h4.w) + bf2f(l4.w);
    }
    ushort4 hi, lo;
    hi.x = f2bf(s0); lo.x = f2bf(s0 - bf2f(hi.x));
    hi.y = f2bf(s1); lo.y = f2bf(s1 - bf2f(hi.y));
    hi.z = f2bf(s2); lo.z = f2bf(s2 - bf2f(hi.z));
    hi.w = f2bf(s3); lo.w = f2bf(s3 - bf2f(hi.w));
    ushort_t* row = hsum_hl + (size_t)j * KA;
    *(ushort4*)&row[m4] = hi;
    *(ushort4*)&row[512 + m4] = lo;
}

// ---------- plain GEMM (bf16x3), 128x128 tile, BK=32, swizzled LDS (0 conflicts) ----------
// MODE 0: fp32 D -> outf (row stride ldout)
// MODE 1: fc epilogue -> outf[jg*512+n] = sum_r sigmoid(D + xf[jg*512+n] + bias_f[n]) * c_prev
template <int MODE>
__global__ __launch_bounds__(256)
void gemm_kernel(int M,
                 const ushort_t* __restrict__ a1,
                 const ushort_t* __restrict__ a2,
                 const ushort_t* __restrict__ b1, const ushort_t* __restrict__ b2,
                 float* __restrict__ outf, int ldout,
                 const float* __restrict__ c_prev, const float* __restrict__ xf,
                 const float* __restrict__ bias_f) {
    __shared__ __align__(16) ushort_t Al[128 * 32];
    __shared__ __align__(16) ushort_t Bl[128 * 32];

    const int tid  = threadIdx.x;
    const int lane = tid & 63, wv = tid >> 6;
    const int l15  = lane & 15, quad = lane >> 4;
    const int wm   = wv >> 1, wn = wv & 1;
    const int m0   = blockIdx.x * 128;
    const int n0   = blockIdx.y * 128;

    const int srow = wv * 16 + (lane >> 2);
    const int kch  = ((lane & 3) ^ ((lane >> 3) & 3)) * 8;
    const int swz  = (quad ^ ((l15 >> 1) & 3)) * 8;

    const ushort_t* a1p[2]; const ushort_t* a2p[2];
    const ushort_t* b1p[2]; const ushort_t* b2p[2];
#pragma unroll
    for (int r = 0; r < 2; ++r) {
        int rl = m0 + srow + r * 64; if (rl > M - 1) rl = M - 1;
        a1p[r] = a1 + (size_t)rl * KA + kch;
        a2p[r] = a2 ? a2 + (size_t)rl * KA + kch : nullptr;
        int nb = n0 + srow + r * 64;
        b1p[r] = b1 + (size_t)nb * KB + kch;
        b2p[r] = b2 ? b2 + (size_t)nb * KB + kch : nullptr;
    }

    f32x4 acc[4][4] = {};
    const int nphase = a2 ? 2 : 1;
    for (int ph = 0; ph < nphase; ++ph) {
        for (int k0 = 0; k0 < KB; k0 += 32) {
            int ka = (k0 < KA) ? k0 : k0 - KA;
            __syncthreads();
#pragma unroll
            for (int r = 0; r < 2; ++r) {
                async_copy16(&Al[(size_t)(wv * 16 + r * 64) * 32], (ph ? a2p[r] : a1p[r]) + ka);
                async_copy16(&Bl[(size_t)(wv * 16 + r * 64) * 32], (ph ? b2p[r] : b1p[r]) + k0);
            }
            __syncthreads();

            short8 aF[4], bF[4];
#pragma unroll
            for (int i = 0; i < 4; ++i) {
                aF[i] = *(const short8*)&Al[(size_t)(wm * 64 + i * 16 + l15) * 32 + swz];
                bF[i] = *(const short8*)&Bl[(size_t)(wn * 64 + i * 16 + l15) * 32 + swz];
            }
#pragma unroll
            for (int i = 0; i < 4; ++i)
#pragma unroll
                for (int j = 0; j < 4; ++j)
                    acc[i][j] = __builtin_amdgcn_mfma_f32_16x16x32_bf16(aF[i], bF[j], acc[i][j], 0, 0, 0);
        }
    }

    if constexpr (MODE == 0) {
#pragma unroll
        for (int i = 0; i < 4; ++i) {
            int mbase = m0 + wm * 64 + i * 16 + quad * 4;
#pragma unroll
            for (int j = 0; j < 4; ++j) {
                int n = n0 + wn * 64 + j * 16 + l15;
#pragma unroll
                for (int r = 0; r < 4; ++r) {
                    int m = mbase + r;
                    if (m < M) outf[(size_t)m * ldout + n] = acc[i][j][r];
                }
            }
        }
    } else {
#pragma unroll
        for (int i = 0; i < 4; ++i) {
            int mbase = m0 + wm * 64 + i * 16 + quad * 4;   // = 4*jg
            if (mbase < M) {
                int jg = mbase >> 2;
#pragma unroll
                for (int j = 0; j < 4; ++j) {
                    int n = n0 + wn * 64 + j * 16 + l15;
                    float add = xf[(size_t)jg * 512 + n] + bias_f[n];
                    float fc = 0.f;
#pragma unroll
                    for (int r = 0; r < 4; ++r) {
                        float f = sigmoidf(acc[i][j][r] + add);
                        fc += f * c_prev[(size_t)(mbase + r) * 512 + n];
                    }
                    outf[(size_t)jg * 512 + n] = fc;
                }
            }
        }
    }
}

// ---------- fused iou-GEMM + LSTM cell ----------
// Block: 128 rows x 64 gate-cols x 3 gates (B rows g*512+n0+..). iou never hits memory.
// NPH=1: leaf (fc=0). NPH=2: dual phase [x | hsum], + fc from f-GEMM.
// Writes c (fp32) and h (hi/lo bf16) directly; `outp` = root h (l==7) or null.
template <int NPH>
__global__ __launch_bounds__(256)
void fused_kernel(int M,
                  const ushort_t* __restrict__ a1,
                  const ushort_t* __restrict__ a2,
                  const ushort_t* __restrict__ b1, const ushort_t* __restrict__ b2,
                  const float* __restrict__ bias_iou,
                  const float* __restrict__ fc,
                  float* __restrict__ c_out,
                  ushort_t* __restrict__ h_out,
                  float* __restrict__ outp) {
    __shared__ __align__(16) ushort_t Al[128 * 32];       // 8 KB
    __shared__ __align__(16) ushort_t Bl[3 * 64 * 32];    // 12 KB

    const int tid  = threadIdx.x;
    const int lane = tid & 63, wv = tid >> 6;
    const int l15  = lane & 15, quad = lane >> 4;
    const int m0   = blockIdx.x * 128;
    const int n0   = blockIdx.y * 64;                     // gate-col tile (8 tiles over 512)

    const int srow = wv * 16 + (lane >> 2);
    const int kch  = ((lane & 3) ^ ((lane >> 3) & 3)) * 8;
    const int swz  = (quad ^ ((l15 >> 1) & 3)) * 8;

    const ushort_t* a1p[2]; const ushort_t* a2p[2];
    const ushort_t* b1p[3]; const ushort_t* b2p[3];
#pragma unroll
    for (int r = 0; r < 2; ++r) {
        int rl = m0 + srow + r * 64; if (rl > M - 1) rl = M - 1;
        a1p[r] = a1 + (size_t)rl * KA + kch;
        a2p[r] = (NPH == 2) ? a2 + (size_t)rl * KA + kch : nullptr;
    }
#pragma unroll
    for (int g = 0; g < 3; ++g) {
        int wrow = g * 512 + n0 + srow;                   // weight row for gate g
        b1p[g] = b1 + (size_t)wrow * KB + kch;
        b2p[g] = (NPH == 2) ? b2 + (size_t)wrow * KB + kch : nullptr;
    }

    f32x4 acc[3][2][4] = {};
    for (int ph = 0; ph < NPH; ++ph) {
        for (int k0 = 0; k0 < KB; k0 += 32) {
            int ka = (k0 < KA) ? k0 : k0 - KA;            // A-side segment-3 wrap
            __syncthreads();
#pragma unroll
            for (int r = 0; r < 2; ++r)
                async_copy16(&Al[(size_t)(wv * 16 + r * 64) * 32], (ph ? a2p[r] : a1p[r]) + ka);
#pragma unroll
            for (int g = 0; g < 3; ++g)
                async_copy16(&Bl[(size_t)(g * 64 + wv * 16) * 32], (ph ? b2p[g] : b1p[g]) + k0);
            __syncthreads();

            short8 aF[2];
#pragma unroll
            for (int i = 0; i < 2; ++i)
                aF[i] = *(const short8*)&Al[(size_t)(wv * 32 + i * 16 + l15) * 32 + swz];
#pragma unroll
            for (int g = 0; g < 3; ++g) {
                short8 bF[4];
#pragma unroll
                for (int j = 0; j < 4; ++j)
                    bF[j] = *(const short8*)&Bl[(size_t)(g * 64 + j * 16 + l15) * 32 + swz];
#pragma unroll
                for (int i = 0; i < 2; ++i)
#pragma unroll
                    for (int j = 0; j < 4; ++j)
                        acc[g][i][j] = __builtin_amdgcn_mfma_f32_16x16x32_bf16(aF[i], bF[j], acc[g][i][j], 0, 0, 0);
            }
        }
    }

    // epilogue: i,o,u in registers -> c, h
#pragma unroll
    for (int i = 0; i < 2; ++i) {
        int mbase = m0 + wv * 32 + i * 16 + quad * 4;
#pragma unroll
        for (int r = 0; r < 4; ++r) {
            int m = mbase + r;
            if (m < M) {
#pragma unroll
                for (int j = 0; j < 4; ++j) {
                    int n = n0 + j * 16 + l15;            // gate-col in [0,512)
                    float iv = sigmoidf(acc[0][i][j][r] + bias_iou[n]);
                    float ov = sigmoidf(acc[1][i][j][r] + bias_iou[512 + n]);
                    float uv = tanhf(  acc[2][i][j][r] + bias_iou[1024 + n]);
                    float c = iv * uv + ((NPH == 2) ? fc[(size_t)m * 512 + n] : 0.f);
                    float h = ov * tanhf(c);
                    c_out[(size_t)m * 512 + n] = c;
                    ushort_t hi = f2bf(h), lo = f2bf(h - bf2f(hi));
                    h_out[(size_t)m * KA + n] = hi;
                    h_out[(size_t)m * KA + 512 + n] = lo;
                    if (outp && m == 0) outp[n] = h;      // root only (M==1)
                }
            }
        }
    }
}

// ---------- host ----------
extern "C" void kernel_launch(void* const* d_in, const int* in_sizes, int n_in,
                              void* d_out, int out_size, void* d_ws, size_t ws_size,
                              hipStream_t stream) {
    const float* x       = (const float*)d_in[0];
    // d_in[1] = children: fixed complete 4-ary tree, contiguous levels — not needed
    const float* W_ioux  = (const float*)d_in[2];
    const float* b_ioux  = (const float*)d_in[3];
    const float* W_iouh  = (const float*)d_in[4];
    const float* b_iouh  = (const float*)d_in[5];
    const float* W_fx    = (const float*)d_in[6];
    const float* b_fx    = (const float*)d_in[7];
    const float* W_fh    = (const float*)d_in[8];
    const float* b_fh    = (const float*)d_in[9];
    float* out = (float*)d_out;
    char* ws = (char*)d_ws;

    ushort_t* WTioux = (ushort_t*)(ws + OFF_WTIOUX);
    ushort_t* WTiouh = (ushort_t*)(ws + OFF_WTIOUH);
    ushort_t* WTfx   = (ushort_t*)(ws + OFF_WTFX);
    ushort_t* WTfh   = (ushort_t*)(ws + OFF_WTFH);
    float*    bias_iou = (float*)(ws + OFF_BIASIOU);
    float*    bias_f   = (float*)(ws + OFF_BIASF);
    ushort_t* x_hl   = (ushort_t*)(ws + OFF_XHL);
    ushort_t* h_int  = x_hl;                       // internal h -> dead leaf-x rows 0..5460
    ushort_t* h_leaf = (ushort_t*)(ws + OFF_HLEAF);
    float*    c_int  = (float*)(ws + OFF_HLEAF);   // aliases h_leaf (live after h_leaf dead)
    float*    xf32   = (float*)(ws + OFF_XF);
    ushort_t* hsum_hl= (ushort_t*)(ws + OFF_HSUM);
    float*    c_leaf = (float*)(ws + OFF_CLEAF);
    float*    fc_buf = (float*)(ws + OFF_FC);

    wsplit_kernel<<<dim3(16, 48), dim3(32, 8), 0, stream>>>(W_ioux, WTioux, 1536);
    wsplit_kernel<<<dim3(16, 48), dim3(32, 8), 0, stream>>>(W_iouh, WTiouh, 1536);
    wsplit_kernel<<<dim3(16, 16), dim3(32, 8), 0, stream>>>(W_fx,   WTfx,   512);
    wsplit_kernel<<<dim3(16, 16), dim3(32, 8), 0, stream>>>(W_fh,   WTfh,   512);
    bias_kernel<<<6, 256, 0, stream>>>(b_ioux, b_iouh, b_fx, b_fh, bias_iou, bias_f);

    // all-node x expansion
    xexp_kernel<<<(NNODE * 128 + 255) / 256, 256, 0, stream>>>(x, x_hl, NNODE * 128);

    // x_f for internal nodes (once): M=5461, N=512
    gemm_kernel<0><<<dim3(43, 4), 256, 0, stream>>>(
        NINT, x_hl + (size_t)NLEAF * KA, nullptr, WTfx, nullptr,
        xf32, 512, nullptr, nullptr, nullptr);

    // ---- leaf level: single fused dispatch (iou never materialized) ----
    fused_kernel<1><<<dim3(128, 8), 256, 0, stream>>>(
        NLEAF, x_hl, nullptr, WTioux, nullptr, bias_iou,
        nullptr, c_leaf, h_leaf, nullptr);

    // ---- internal levels ----
    const int sizes[8] = {16384, 4096, 1024, 256, 64, 16, 4, 1};
    int off = 0;
    for (int l = 1; l < 8; ++l) {
        int off_prev = off;
        off += sizes[l - 1];
        int ioff = off - NLEAF;
        int nl = sizes[l];
        int M4 = 4 * nl;
        int n4 = nl * 128;

        const ushort_t* child_h = (l == 1) ? h_leaf
                                           : h_int + (size_t)(off_prev - NLEAF) * KA;
        const float*    child_c = (l == 1) ? c_leaf
                                           : c_int + (size_t)(off_prev - NLEAF) * 512;

        hsum_kernel<<<(n4 + 255) / 256, 256, 0, stream>>>(child_h, hsum_hl, n4);

        // f gates + fc reduction: h_child@W_fh, x_f[parent]+bias in epilogue
        gemm_kernel<1><<<dim3((M4 + 127) / 128, 4), 256, 0, stream>>>(
            M4, child_h, nullptr, WTfh, nullptr,
            fc_buf, 512, child_c, xf32 + (size_t)ioff * 512, bias_f);

        // fused iou-GEMM + cell: dual phase [x_level | hsum]
        fused_kernel<2><<<dim3((nl + 127) / 128, 8), 256, 0, stream>>>(
            nl, x_hl + (size_t)off * KA, hsum_hl, WTioux, WTiouh, bias_iou,
            fc_buf, c_int + (size_t)ioff * 512, h_int + (size_t)ioff * KA,
            (l == 7) ? out : nullptr);
    }
    (void)d_in; (void)in_sizes; (void)n_in; (void)out_size; (void)ws_size;
}

// Round 7
// 730.045 us; speedup vs baseline: 1.4726x; 1.4726x over previous
//
#include <hip/hip_runtime.h>
#include <cstdint>

// ---------- types ----------
using short8 = __attribute__((ext_vector_type(8))) short;
using f32x4  = __attribute__((ext_vector_type(4))) float;
typedef unsigned short ushort_t;

// ---------- bf16 helpers ----------
__device__ __forceinline__ ushort_t f2bf(float f) {
    union { float f; unsigned int u; } v; v.f = f;
    unsigned int r = v.u + 0x7FFFu + ((v.u >> 16) & 1u);   // RNE
    return (ushort_t)(r >> 16);
}
__device__ __forceinline__ float bf2f(ushort_t s) {
    union { unsigned int u; float f; } v; v.u = ((unsigned int)s) << 16;
    return v.f;
}
__device__ __forceinline__ float sigmoidf(float x) { return 1.f / (1.f + expf(-x)); }

__device__ __forceinline__ void async_copy16(void* lds, const void* g) {
    __builtin_amdgcn_global_load_lds((__attribute__((address_space(1))) void*)g,
                                     (__attribute__((address_space(3))) void*)lds,
                                     16, 0, 0);
}

// ---------- constants ----------
// complete 4-ary tree, leaves-first: levels 16384 4096 1024 256 64 16 4 1 (N=21845)
// bf16x3: effective K=1536. A-side stored [hi|lo] (KA=1024), 3rd segment re-reads hi
// via pointer wrap. B-side stored [hi|hi|lo] (KB=1536).
#define KA 1024
#define KB 1536
#define NLEAF 16384
#define NNODE 21845
#define NINT  5461

// ---------- workspace layout (bytes), total 152,412,160 (~152.4 MB, = R6 proven) ----------
#define OFF_WTIOUX  0UL
#define OFF_WTIOUH  (OFF_WTIOUX + 1536UL*KB*2)
#define OFF_WTFX    (OFF_WTIOUH + 1536UL*KB*2)
#define OFF_WTFH    (OFF_WTFX   + 512UL*KB*2)
#define OFF_BIASIOU (OFF_WTFH   + 512UL*KB*2)
#define OFF_BIASF   (OFF_BIASIOU + 1536UL*4)
#define OFF_XHL     (OFF_BIASF  + 512UL*4)
// x_hl: 21848 rows x [hi|lo].
//   rows 0..5460      -> h_int after leaf (leaf x dead by then)
//   rows 5464..16383  -> iou scratch for internal levels (bf16 l1: 6144 rows; fp32 l>=2: 3072 rows)
//   rows 16384..21844 -> internal x (live until each level's combined dispatch)
#define OFF_HLEAF   (OFF_XHL    + 21848UL*KA*2)
// h_leaf: 16384 x [hi|lo] = 33.5 MB; its first 11.2 MB double as c_int after l1's
// hsum/f-path consume h_leaf (c_int first written by l1's cell, which runs after).
#define OFF_XF      (OFF_HLEAF  + 16384UL*KA*2)
#define OFF_HSUM    (OFF_XF     + 5464UL*512*4)
#define OFF_CLEAF   (OFF_HSUM   + 4096UL*KA*2)
#define OFF_FC      (OFF_CLEAF  + 16384UL*512*4)
// end = OFF_FC + 4096*512*4 = 152,412,160

// ---------- prep: transpose fp32 W (KxN) -> N x KB bf16, B-side [hi|hi|lo] ----------
__global__ void wsplit_kernel(const float* __restrict__ in, ushort_t* __restrict__ out, int N) {
    __shared__ float t[32][33];
    int kb = blockIdx.x * 32, nb = blockIdx.y * 32;
    for (int i = threadIdx.y; i < 32; i += 8)
        t[i][threadIdx.x] = in[(size_t)(kb + i) * N + nb + threadIdx.x];
    __syncthreads();
    for (int i = threadIdx.y; i < 32; i += 8) {
        float v = t[threadIdx.x][i];
        ushort_t hi = f2bf(v);
        ushort_t lo = f2bf(v - bf2f(hi));
        size_t row = (size_t)(nb + i) * KB + kb + threadIdx.x;
        out[row]        = hi;   // pairs with A hi
        out[row + 512]  = hi;   // pairs with A lo
        out[row + 1024] = lo;   // pairs with A hi (wrapped)
    }
}

__global__ void bias_kernel(const float* __restrict__ b_ioux, const float* __restrict__ b_iouh,
                            const float* __restrict__ b_fx, const float* __restrict__ b_fh,
                            float* __restrict__ bias_iou, float* __restrict__ bias_f) {
    int t = blockIdx.x * blockDim.x + threadIdx.x;
    if (t < 1536) bias_iou[t] = b_ioux[t] + b_iouh[t];
    if (t < 512)  bias_f[t]   = b_fx[t] + b_fh[t];
}

// ---------- all x rows -> A-side [hi|lo], 4 elems/thread ----------
__global__ void xexp_kernel(const float* __restrict__ x, ushort_t* __restrict__ xe, int n4) {
    int t = blockIdx.x * blockDim.x + threadIdx.x;
    if (t >= n4) return;
    int j = t >> 7, m4 = (t & 127) * 4;
    float4 v = *(const float4*)&x[(size_t)j * 512 + m4];
    ushort4 hi, lo;
    hi.x = f2bf(v.x); lo.x = f2bf(v.x - bf2f(hi.x));
    hi.y = f2bf(v.y); lo.y = f2bf(v.y - bf2f(hi.y));
    hi.z = f2bf(v.z); lo.z = f2bf(v.z - bf2f(hi.z));
    hi.w = f2bf(v.w); lo.w = f2bf(v.w - bf2f(hi.w));
    ushort_t* row = xe + (size_t)j * KA;
    *(ushort4*)&row[m4] = hi;
    *(ushort4*)&row[512 + m4] = lo;
}

// ---------- hsum of 4 children (exact h = hi+lo) -> A-side [hi|lo] ----------
__global__ void hsum_kernel(const ushort_t* __restrict__ h_hl, ushort_t* __restrict__ hsum_hl,
                            int n4) {
    int t = blockIdx.x * blockDim.x + threadIdx.x;
    if (t >= n4) return;
    int j = t >> 7, m4 = (t & 127) * 4;
    const ushort_t* base = h_hl + (size_t)(4 * j) * KA;
    float s0 = 0.f, s1 = 0.f, s2 = 0.f, s3 = 0.f;
#pragma unroll
    for (int r = 0; r < 4; ++r) {
        ushort4 h4 = *(const ushort4*)&base[(size_t)r * KA + m4];
        ushort4 l4 = *(const ushort4*)&base[(size_t)r * KA + 512 + m4];
        s0 += bf2f(h4.x) + bf2f(l4.x);
        s1 += bf2f(h4.y) + bf2f(l4.y);
        s2 += bf2f(h4.z) + bf2f(l4.z);
        s3 += bf2f(h4.w) + bf2f(l4.w);
    }
    ushort4 hi, lo;
    hi.x = f2bf(s0); lo.x = f2bf(s0 - bf2f(hi.x));
    hi.y = f2bf(s1); lo.y = f2bf(s1 - bf2f(hi.y));
    hi.z = f2bf(s2); lo.z = f2bf(s2 - bf2f(hi.z));
    hi.w = f2bf(s3); lo.w = f2bf(s3 - bf2f(hi.w));
    ushort_t* row = hsum_hl + (size_t)j * KA;
    *(ushort4*)&row[m4] = hi;
    *(ushort4*)&row[512 + m4] = lo;
}

// ---------- plain GEMM (bf16x3): used only for the one-shot x_f precompute ----------
__global__ __launch_bounds__(256)
void gemm_kernel(int M,
                 const ushort_t* __restrict__ a1,
                 const ushort_t* __restrict__ b1,
                 float* __restrict__ outf, int ldout) {
    __shared__ __align__(16) ushort_t Al[128 * 32];
    __shared__ __align__(16) ushort_t Bl[128 * 32];

    const int tid  = threadIdx.x;
    const int lane = tid & 63, wv = tid >> 6;
    const int l15  = lane & 15, quad = lane >> 4;
    const int wm   = wv >> 1, wn = wv & 1;
    const int m0   = blockIdx.x * 128;
    const int n0   = blockIdx.y * 128;

    const int srow = wv * 16 + (lane >> 2);
    const int kch  = ((lane & 3) ^ ((lane >> 3) & 3)) * 8;
    const int swz  = (quad ^ ((l15 >> 1) & 3)) * 8;

    const ushort_t* a1p[2]; const ushort_t* b1p[2];
#pragma unroll
    for (int r = 0; r < 2; ++r) {
        int rl = m0 + srow + r * 64; if (rl > M - 1) rl = M - 1;
        a1p[r] = a1 + (size_t)rl * KA + kch;
        int nb = n0 + srow + r * 64;
        b1p[r] = b1 + (size_t)nb * KB + kch;
    }

    f32x4 acc[4][4] = {};
    for (int k0 = 0; k0 < KB; k0 += 32) {
        int ka = (k0 < KA) ? k0 : k0 - KA;
        __syncthreads();
#pragma unroll
        for (int r = 0; r < 2; ++r) {
            async_copy16(&Al[(size_t)(wv * 16 + r * 64) * 32], a1p[r] + ka);
            async_copy16(&Bl[(size_t)(wv * 16 + r * 64) * 32], b1p[r] + k0);
        }
        __syncthreads();

        short8 aF[4], bF[4];
#pragma unroll
        for (int i = 0; i < 4; ++i) {
            aF[i] = *(const short8*)&Al[(size_t)(wm * 64 + i * 16 + l15) * 32 + swz];
            bF[i] = *(const short8*)&Bl[(size_t)(wn * 64 + i * 16 + l15) * 32 + swz];
        }
#pragma unroll
        for (int i = 0; i < 4; ++i)
#pragma unroll
            for (int j = 0; j < 4; ++j)
                acc[i][j] = __builtin_amdgcn_mfma_f32_16x16x32_bf16(aF[i], bF[j], acc[i][j], 0, 0, 0);
    }

#pragma unroll
    for (int i = 0; i < 4; ++i) {
        int mbase = m0 + wm * 64 + i * 16 + quad * 4;
#pragma unroll
        for (int j = 0; j < 4; ++j) {
            int n = n0 + wn * 64 + j * 16 + l15;
#pragma unroll
            for (int r = 0; r < 4; ++r) {
                int m = mbase + r;
                if (m < M) outf[(size_t)m * ldout + n] = acc[i][j][r];
            }
        }
    }
}

// ---------- combined per-level dispatch: blockIdx.y<4 -> f-path, else iou-path ----------
// f-path:   D = child_h @ Wfh (M=4nl, N=512);  fc_out[jg] = sum_r sigmoid(D+xf+bias_f)*c_prev
// iou-path: D = [x|hsum] @ [Wioux;Wiouh] (M=nl, N=1536) -> iou_b (bf16) or iou_f (fp32)
__global__ __launch_bounds__(256)
void combined_kernel(int nl,
                     const ushort_t* __restrict__ child_h, const float* __restrict__ c_prev,
                     const float* __restrict__ xf, const float* __restrict__ bias_f,
                     float* __restrict__ fc_out,
                     const ushort_t* __restrict__ x_lvl, const ushort_t* __restrict__ hsum,
                     const ushort_t* __restrict__ Wfh,
                     const ushort_t* __restrict__ Wioux, const ushort_t* __restrict__ Wiouh,
                     float* __restrict__ iou_f, ushort_t* __restrict__ iou_b) {
    __shared__ __align__(16) ushort_t Al[128 * 32];
    __shared__ __align__(16) ushort_t Bl[128 * 32];

    const int by = blockIdx.y;
    const bool fpath = by < 4;
    const int M = fpath ? 4 * nl : nl;
    const int m0 = blockIdx.x * 128;
    if (m0 >= M) return;
    const int n0 = (fpath ? by : by - 4) * 128;

    const ushort_t* A1 = fpath ? child_h : x_lvl;
    const ushort_t* A2 = fpath ? nullptr : hsum;
    const ushort_t* B1 = fpath ? Wfh : Wioux;
    const ushort_t* B2 = fpath ? nullptr : Wiouh;

    const int tid  = threadIdx.x;
    const int lane = tid & 63, wv = tid >> 6;
    const int l15  = lane & 15, quad = lane >> 4;
    const int wm   = wv >> 1, wn = wv & 1;

    const int srow = wv * 16 + (lane >> 2);
    const int kch  = ((lane & 3) ^ ((lane >> 3) & 3)) * 8;
    const int swz  = (quad ^ ((l15 >> 1) & 3)) * 8;

    const ushort_t* a1p[2]; const ushort_t* a2p[2];
    const ushort_t* b1p[2]; const ushort_t* b2p[2];
#pragma unroll
    for (int r = 0; r < 2; ++r) {
        int rl = m0 + srow + r * 64; if (rl > M - 1) rl = M - 1;
        a1p[r] = A1 + (size_t)rl * KA + kch;
        a2p[r] = A2 ? A2 + (size_t)rl * KA + kch : nullptr;
        int nb = n0 + srow + r * 64;
        b1p[r] = B1 + (size_t)nb * KB + kch;
        b2p[r] = B2 ? B2 + (size_t)nb * KB + kch : nullptr;
    }

    f32x4 acc[4][4] = {};
    const int nphase = A2 ? 2 : 1;
    for (int ph = 0; ph < nphase; ++ph) {
        for (int k0 = 0; k0 < KB; k0 += 32) {
            int ka = (k0 < KA) ? k0 : k0 - KA;
            __syncthreads();
#pragma unroll
            for (int r = 0; r < 2; ++r) {
                async_copy16(&Al[(size_t)(wv * 16 + r * 64) * 32], (ph ? a2p[r] : a1p[r]) + ka);
                async_copy16(&Bl[(size_t)(wv * 16 + r * 64) * 32], (ph ? b2p[r] : b1p[r]) + k0);
            }
            __syncthreads();

            short8 aF[4], bF[4];
#pragma unroll
            for (int i = 0; i < 4; ++i) {
                aF[i] = *(const short8*)&Al[(size_t)(wm * 64 + i * 16 + l15) * 32 + swz];
                bF[i] = *(const short8*)&Bl[(size_t)(wn * 64 + i * 16 + l15) * 32 + swz];
            }
#pragma unroll
            for (int i = 0; i < 4; ++i)
#pragma unroll
                for (int j = 0; j < 4; ++j)
                    acc[i][j] = __builtin_amdgcn_mfma_f32_16x16x32_bf16(aF[i], bF[j], acc[i][j], 0, 0, 0);
        }
    }

    if (fpath) {
#pragma unroll
        for (int i = 0; i < 4; ++i) {
            int mbase = m0 + wm * 64 + i * 16 + quad * 4;   // = 4*jg
            if (mbase < M) {
                int jg = mbase >> 2;
#pragma unroll
                for (int j = 0; j < 4; ++j) {
                    int n = n0 + wn * 64 + j * 16 + l15;
                    float add = xf[(size_t)jg * 512 + n] + bias_f[n];
                    float fc = 0.f;
#pragma unroll
                    for (int r = 0; r < 4; ++r) {
                        float f = sigmoidf(acc[i][j][r] + add);
                        fc += f * c_prev[(size_t)(mbase + r) * 512 + n];
                    }
                    fc_out[(size_t)jg * 512 + n] = fc;
                }
            }
        }
    } else {
#pragma unroll
        for (int i = 0; i < 4; ++i) {
            int mbase = m0 + wm * 64 + i * 16 + quad * 4;
#pragma unroll
            for (int j = 0; j < 4; ++j) {
                int n = n0 + wn * 64 + j * 16 + l15;
#pragma unroll
                for (int r = 0; r < 4; ++r) {
                    int m = mbase + r;
                    if (m < M) {
                        if (iou_b) iou_b[(size_t)m * 1536 + n] = f2bf(acc[i][j][r]);
                        else       iou_f[(size_t)m * 1536 + n] = acc[i][j][r];
                    }
                }
            }
        }
    }
}

// ---------- fused leaf: iou-GEMM + LSTM cell in-register (measured 136 us, R6) ----------
__global__ __launch_bounds__(256)
void fused_leaf_kernel(int M,
                       const ushort_t* __restrict__ a1,
                       const ushort_t* __restrict__ b1,
                       const float* __restrict__ bias_iou,
                       float* __restrict__ c_out,
                       ushort_t* __restrict__ h_out) {
    __shared__ __align__(16) ushort_t Al[128 * 32];       // 8 KB
    __shared__ __align__(16) ushort_t Bl[3 * 64 * 32];    // 12 KB

    const int tid  = threadIdx.x;
    const int lane = tid & 63, wv = tid >> 6;
    const int l15  = lane & 15, quad = lane >> 4;
    const int m0   = blockIdx.x * 128;
    const int n0   = blockIdx.y * 64;

    const int srow = wv * 16 + (lane >> 2);
    const int kch  = ((lane & 3) ^ ((lane >> 3) & 3)) * 8;
    const int swz  = (quad ^ ((l15 >> 1) & 3)) * 8;

    const ushort_t* a1p[2]; const ushort_t* b1p[3];
#pragma unroll
    for (int r = 0; r < 2; ++r) {
        int rl = m0 + srow + r * 64; if (rl > M - 1) rl = M - 1;
        a1p[r] = a1 + (size_t)rl * KA + kch;
    }
#pragma unroll
    for (int g = 0; g < 3; ++g)
        b1p[g] = b1 + (size_t)(g * 512 + n0 + srow) * KB + kch;

    f32x4 acc[3][2][4] = {};
    for (int k0 = 0; k0 < KB; k0 += 32) {
        int ka = (k0 < KA) ? k0 : k0 - KA;
        __syncthreads();
#pragma unroll
        for (int r = 0; r < 2; ++r)
            async_copy16(&Al[(size_t)(wv * 16 + r * 64) * 32], a1p[r] + ka);
#pragma unroll
        for (int g = 0; g < 3; ++g)
            async_copy16(&Bl[(size_t)(g * 64 + wv * 16) * 32], b1p[g] + k0);
        __syncthreads();

        short8 aF[2];
#pragma unroll
        for (int i = 0; i < 2; ++i)
            aF[i] = *(const short8*)&Al[(size_t)(wv * 32 + i * 16 + l15) * 32 + swz];
#pragma unroll
        for (int g = 0; g < 3; ++g) {
            short8 bF[4];
#pragma unroll
            for (int j = 0; j < 4; ++j)
                bF[j] = *(const short8*)&Bl[(size_t)(g * 64 + j * 16 + l15) * 32 + swz];
#pragma unroll
            for (int i = 0; i < 2; ++i)
#pragma unroll
                for (int j = 0; j < 4; ++j)
                    acc[g][i][j] = __builtin_amdgcn_mfma_f32_16x16x32_bf16(aF[i], bF[j], acc[g][i][j], 0, 0, 0);
        }
    }

#pragma unroll
    for (int i = 0; i < 2; ++i) {
        int mbase = m0 + wv * 32 + i * 16 + quad * 4;
#pragma unroll
        for (int r = 0; r < 4; ++r) {
            int m = mbase + r;
            if (m < M) {
#pragma unroll
                for (int j = 0; j < 4; ++j) {
                    int n = n0 + j * 16 + l15;
                    float iv = sigmoidf(acc[0][i][j][r] + bias_iou[n]);
                    float ov = sigmoidf(acc[1][i][j][r] + bias_iou[512 + n]);
                    float uv = tanhf(  acc[2][i][j][r] + bias_iou[1024 + n]);
                    float c = iv * uv;
                    float h = ov * tanhf(c);
                    c_out[(size_t)m * 512 + n] = c;
                    ushort_t hi = f2bf(h), lo = f2bf(h - bf2f(hi));
                    h_out[(size_t)m * KA + n] = hi;
                    h_out[(size_t)m * KA + 512 + n] = lo;
                }
            }
        }
    }
}

// ---------- elementwise cell (internal levels), 4 elems/thread ----------
template <bool IOU_BF>
__global__ void cell_kernel(const void* __restrict__ iou_v, const float* __restrict__ bias_iou,
                            const float* __restrict__ fc,
                            ushort_t* __restrict__ h_out, float* __restrict__ c_out,
                            int n4, float* __restrict__ outp) {
    int t = blockIdx.x * blockDim.x + threadIdx.x;
    if (t >= n4) return;
    int j = t >> 7, m4 = (t & 127) * 4;
    float pi[4], po[4], pu[4];
    if constexpr (IOU_BF) {
        const ushort_t* row = (const ushort_t*)iou_v + (size_t)j * 1536;
        ushort4 a = *(const ushort4*)&row[m4];
        ushort4 b = *(const ushort4*)&row[512 + m4];
        ushort4 c = *(const ushort4*)&row[1024 + m4];
        pi[0]=bf2f(a.x); pi[1]=bf2f(a.y); pi[2]=bf2f(a.z); pi[3]=bf2f(a.w);
        po[0]=bf2f(b.x); po[1]=bf2f(b.y); po[2]=bf2f(b.z); po[3]=bf2f(b.w);
        pu[0]=bf2f(c.x); pu[1]=bf2f(c.y); pu[2]=bf2f(c.z); pu[3]=bf2f(c.w);
    } else {
        const float* row = (const float*)iou_v + (size_t)j * 1536;
        float4 a = *(const float4*)&row[m4];
        float4 b = *(const float4*)&row[512 + m4];
        float4 c = *(const float4*)&row[1024 + m4];
        pi[0]=a.x; pi[1]=a.y; pi[2]=a.z; pi[3]=a.w;
        po[0]=b.x; po[1]=b.y; po[2]=b.z; po[3]=b.w;
        pu[0]=c.x; pu[1]=c.y; pu[2]=c.z; pu[3]=c.w;
    }
    float4 bi = *(const float4*)&bias_iou[m4];
    float4 bo = *(const float4*)&bias_iou[512 + m4];
    float4 bu = *(const float4*)&bias_iou[1024 + m4];
    float4 fcv = *(const float4*)&fc[(size_t)j * 512 + m4];
    float bia[4] = {bi.x, bi.y, bi.z, bi.w};
    float boa[4] = {bo.x, bo.y, bo.z, bo.w};
    float bua[4] = {bu.x, bu.y, bu.z, bu.w};
    float fca[4] = {fcv.x, fcv.y, fcv.z, fcv.w};
    float cv[4], hv[4];
#pragma unroll
    for (int q = 0; q < 4; ++q) {
        float iv = sigmoidf(pi[q] + bia[q]);
        float ov = sigmoidf(po[q] + boa[q]);
        float uv = tanhf(  pu[q] + bua[q]);
        cv[q] = iv * uv + fca[q];
        hv[q] = ov * tanhf(cv[q]);
    }
    *(float4*)&c_out[(size_t)j * 512 + m4] = float4{cv[0], cv[1], cv[2], cv[3]};
    ushort4 hi, lo;
    hi.x = f2bf(hv[0]); lo.x = f2bf(hv[0] - bf2f(hi.x));
    hi.y = f2bf(hv[1]); lo.y = f2bf(hv[1] - bf2f(hi.y));
    hi.z = f2bf(hv[2]); lo.z = f2bf(hv[2] - bf2f(hi.z));
    hi.w = f2bf(hv[3]); lo.w = f2bf(hv[3] - bf2f(hi.w));
    ushort_t* hr = h_out + (size_t)j * KA;
    *(ushort4*)&hr[m4] = hi;
    *(ushort4*)&hr[512 + m4] = lo;
    if (outp) *(float4*)&outp[m4] = float4{hv[0], hv[1], hv[2], hv[3]};   // root (nl==1)
}

// ---------- host ----------
extern "C" void kernel_launch(void* const* d_in, const int* in_sizes, int n_in,
                              void* d_out, int out_size, void* d_ws, size_t ws_size,
                              hipStream_t stream) {
    const float* x       = (const float*)d_in[0];
    // d_in[1] = children: fixed complete 4-ary tree, contiguous levels — not needed
    const float* W_ioux  = (const float*)d_in[2];
    const float* b_ioux  = (const float*)d_in[3];
    const float* W_iouh  = (const float*)d_in[4];
    const float* b_iouh  = (const float*)d_in[5];
    const float* W_fx    = (const float*)d_in[6];
    const float* b_fx    = (const float*)d_in[7];
    const float* W_fh    = (const float*)d_in[8];
    const float* b_fh    = (const float*)d_in[9];
    float* out = (float*)d_out;
    char* ws = (char*)d_ws;

    ushort_t* WTioux = (ushort_t*)(ws + OFF_WTIOUX);
    ushort_t* WTiouh = (ushort_t*)(ws + OFF_WTIOUH);
    ushort_t* WTfx   = (ushort_t*)(ws + OFF_WTFX);
    ushort_t* WTfh   = (ushort_t*)(ws + OFF_WTFH);
    float*    bias_iou = (float*)(ws + OFF_BIASIOU);
    float*    bias_f   = (float*)(ws + OFF_BIASF);
    ushort_t* x_hl   = (ushort_t*)(ws + OFF_XHL);
    ushort_t* h_int  = x_hl;                               // rows 0..5460 (dead leaf x)
    ushort_t* iou_b  = x_hl + (size_t)5464 * KA;           // rows 5464.. (dead leaf x)
    float*    iou_f  = (float*)iou_b;
    ushort_t* h_leaf = (ushort_t*)(ws + OFF_HLEAF);
    float*    c_int  = (float*)(ws + OFF_HLEAF);           // alias; live after h_leaf dead
    float*    xf32   = (float*)(ws + OFF_XF);
    ushort_t* hsum_hl= (ushort_t*)(ws + OFF_HSUM);
    float*    c_leaf = (float*)(ws + OFF_CLEAF);
    float*    fc_buf = (float*)(ws + OFF_FC);

    wsplit_kernel<<<dim3(16, 48), dim3(32, 8), 0, stream>>>(W_ioux, WTioux, 1536);
    wsplit_kernel<<<dim3(16, 48), dim3(32, 8), 0, stream>>>(W_iouh, WTiouh, 1536);
    wsplit_kernel<<<dim3(16, 16), dim3(32, 8), 0, stream>>>(W_fx,   WTfx,   512);
    wsplit_kernel<<<dim3(16, 16), dim3(32, 8), 0, stream>>>(W_fh,   WTfh,   512);
    bias_kernel<<<6, 256, 0, stream>>>(b_ioux, b_iouh, b_fx, b_fh, bias_iou, bias_f);

    // all-node x expansion
    xexp_kernel<<<(NNODE * 128 + 255) / 256, 256, 0, stream>>>(x, x_hl, NNODE * 128);

    // x_f for internal nodes (once): M=5461, N=512
    gemm_kernel<<<dim3(43, 4), 256, 0, stream>>>(
        NINT, x_hl + (size_t)NLEAF * KA, WTfx, xf32, 512);

    // ---- leaf level: fused iou-GEMM + cell (no iou materialization) ----
    fused_leaf_kernel<<<dim3(128, 8), 256, 0, stream>>>(
        NLEAF, x_hl, WTioux, bias_iou, c_leaf, h_leaf);

    // ---- internal levels: hsum -> combined(f || iou) -> cell ----
    const int sizes[8] = {16384, 4096, 1024, 256, 64, 16, 4, 1};
    int off = 0;
    for (int l = 1; l < 8; ++l) {
        int off_prev = off;
        off += sizes[l - 1];
        int ioff = off - NLEAF;
        int nl = sizes[l];
        int M4 = 4 * nl;
        int n4 = nl * 128;

        const ushort_t* child_h = (l == 1) ? h_leaf : h_int + (size_t)(off_prev - NLEAF) * KA;
        const float*    child_c = (l == 1) ? c_leaf : c_int + (size_t)(off_prev - NLEAF) * 512;

        hsum_kernel<<<(n4 + 255) / 256, 256, 0, stream>>>(child_h, hsum_hl, n4);

        bool use_bf = (l == 1);   // l1 iou in bf16 (12.6 MB), l>=2 fp32 (<=6.3 MB)
        combined_kernel<<<dim3((M4 + 127) / 128, 16), 256, 0, stream>>>(
            nl, child_h, child_c, xf32 + (size_t)ioff * 512, bias_f, fc_buf,
            x_hl + (size_t)off * KA, hsum_hl, WTfh, WTioux, WTiouh,
            use_bf ? nullptr : iou_f, use_bf ? iou_b : nullptr);

        if (use_bf)
            cell_kernel<true><<<(n4 + 255) / 256, 256, 0, stream>>>(
                iou_b, bias_iou, fc_buf, h_int + (size_t)ioff * KA,
                c_int + (size_t)ioff * 512, n4, nullptr);
        else
            cell_kernel<false><<<(n4 + 255) / 256, 256, 0, stream>>>(
                iou_f, bias_iou, fc_buf, h_int + (size_t)ioff * KA,
                c_int + (size_t)ioff * 512, n4, (l == 7) ? out : nullptr);
    }
    (void)d_in; (void)in_sizes; (void)n_in; (void)out_size; (void)ws_size;
}